// Round 4
// baseline (81.799 us; speedup 1.0000x reference)
//
#include <hip/hip_runtime.h>

typedef _Float16 f16x8 __attribute__((ext_vector_type(8)));
typedef __fp16 fp16x2 __attribute__((ext_vector_type(2)));
typedef float f32x4 __attribute__((ext_vector_type(4)));

#define B_SZ 16384
#define BC (B_SZ * 256)

__device__ __forceinline__ f16x8 cvt8(f32x4 a, f32x4 b) {
  fp16x2 p0 = __builtin_amdgcn_cvt_pkrtz(a[0], a[1]);
  fp16x2 p1 = __builtin_amdgcn_cvt_pkrtz(a[2], a[3]);
  fp16x2 p2 = __builtin_amdgcn_cvt_pkrtz(b[0], b[1]);
  fp16x2 p3 = __builtin_amdgcn_cvt_pkrtz(b[2], b[3]);
  f16x8 o;
  o[0] = (_Float16)p0[0]; o[1] = (_Float16)p0[1];
  o[2] = (_Float16)p1[0]; o[3] = (_Float16)p1[1];
  o[4] = (_Float16)p2[0]; o[5] = (_Float16)p2[1];
  o[6] = (_Float16)p3[0]; o[7] = (_Float16)p3[1];
  return o;
}

__device__ __forceinline__ float tanh_fast(float v) {
  float a = fminf(fabsf(v), 18.f);
  float t = __expf(2.f * a);
  float r = (t - 1.f) * __builtin_amdgcn_rcpf(t + 1.f);
  return copysignf(r, v);
}

// Pack Wu/Wg/Wa/Wd into fragment-major f16 layout:
// wsB[(((kc*8 + w)*8 + f)*64 + l15*4 + lg)*8 + b] = W_s[c][k], where
//   f = g*4 + s, c = w*32 + g*16 + l15, k = kc*32 + lg*8 + b.
// A wave's fragment load (fixed kc,w,f; lanes (l15,lg)) is a bijection onto
// one contiguous 1 KB region -> fully coalesced. s=0 is Wu (K-pad >=256: zeros).
__global__ __launch_bounds__(256) void pack_w(const float* __restrict__ Wu,
                                              const float* __restrict__ Wg,
                                              const float* __restrict__ Wa,
                                              const float* __restrict__ Wd,
                                              _Float16* __restrict__ wsB) {
  int tid = blockIdx.x * 256 + threadIdx.x;  // 65536 total
  int lg = tid & 3;
  int l15 = (tid >> 2) & 15;
  int f = (tid >> 6) & 7;
  int w = (tid >> 9) & 7;
  int kc = tid >> 12;
  int s = f & 3;
  int g = f >> 2;
  int c = w * 32 + g * 16 + l15;
  int k0 = kc * 32 + lg * 8;
  float v[8];
  if (s == 0) {
    if (k0 < 256) {
      const float* p = Wu + (size_t)c * 256 + k0;
#pragma unroll
      for (int i = 0; i < 8; ++i) v[i] = p[i];
    } else {
#pragma unroll
      for (int i = 0; i < 8; ++i) v[i] = 0.f;
    }
  } else {
    const float* p = (s == 1 ? Wg : (s == 2 ? Wa : Wd)) + (size_t)c * 512 + k0;
#pragma unroll
    for (int i = 0; i < 8; ++i) v[i] = p[i];
  }
  f32x4 a = {v[0], v[1], v[2], v[3]};
  f32x4 b = {v[4], v[5], v[6], v[7]};
  *reinterpret_cast<f16x8*>(wsB + (size_t)tid * 8) = cvt8(a, b);
}

// Zero-LDS, zero-barrier fused GEMM+epilogue.
// Wave tile: 32 rows x 32 c (x4 matrices packed in N). 4096 waves, all
// independent. A direct from x/h (f32->f16 in reg), B direct from packed wsB.
__global__ __launch_bounds__(256, 4) void rwa_main(
    const float* __restrict__ x, const float* __restrict__ nt_,
    const float* __restrict__ dt_, const float* __restrict__ h,
    const float* __restrict__ amax_, const float* __restrict__ bu,
    const float* __restrict__ bg, const _Float16* __restrict__ wsB,
    float* __restrict__ out) {
  const int tid = threadIdx.x;
  const int lane = tid & 63;
  const int l15 = lane & 15;
  const int lg = lane >> 4;
  const int wid = blockIdx.x * 4 + (tid >> 6);  // 0..4095
  const int w = wid & 7;                        // 32-wide c chunk
  const int row0 = (wid >> 3) * 32;

  const float* xr0 = x + (size_t)(row0 + l15) * 256 + lg * 8;
  const float* hr0 = h + (size_t)(row0 + l15) * 256 + lg * 8;
  const float* xr1 = xr0 + 16 * 256;
  const float* hr1 = hr0 + 16 * 256;
  const _Float16* bb = wsB + (size_t)w * 4096 + (l15 * 4 + lg) * 8;

  f32x4 acc[2][2][4] = {};  // [mi][g][s]

#pragma unroll
  for (int kc = 0; kc < 16; ++kc) {
    const float* r0 = (kc < 8 ? xr0 : hr0) + (kc & 7) * 32;
    const float* r1 = (kc < 8 ? xr1 : hr1) + (kc & 7) * 32;
    f16x8 af0 = cvt8(*reinterpret_cast<const f32x4*>(r0),
                     *reinterpret_cast<const f32x4*>(r0 + 4));
    f16x8 af1 = cvt8(*reinterpret_cast<const f32x4*>(r1),
                     *reinterpret_cast<const f32x4*>(r1 + 4));
    const _Float16* bk = bb + (size_t)kc * 32768;
#pragma unroll
    for (int g = 0; g < 2; ++g) {
#pragma unroll
      for (int s = 0; s < 4; ++s) {
        if (s == 0 && kc >= 8) continue;  // Wu zero-pad: skip load+MFMA
        f16x8 bf = *reinterpret_cast<const f16x8*>(bk + (g * 4 + s) * 512);
        acc[0][g][s] =
            __builtin_amdgcn_mfma_f32_16x16x32_f16(af0, bf, acc[0][g][s], 0, 0, 0);
        acc[1][g][s] =
            __builtin_amdgcn_mfma_f32_16x16x32_f16(af1, bf, acc[1][g][s], 0, 0, 0);
      }
    }
  }

  // Epilogue: lane owns (r, c) with u,g,a,dec all local.
  // C/D layout: col = l15, row = lg*4 + rg (+ mi*16).
#pragma unroll
  for (int g = 0; g < 2; ++g) {
    const int c = w * 32 + g * 16 + l15;
    const float buv = bu[c];
    const float bgv = bg[c];
#pragma unroll
    for (int mi = 0; mi < 2; ++mi) {
#pragma unroll
      for (int rg = 0; rg < 4; ++rg) {
        const int r = row0 + mi * 16 + lg * 4 + rg;
        const int idx = r * 256 + c;
        const float u = acc[mi][g][0][rg] + buv;
        const float gt = acc[mi][g][1][rg] + bgv;
        const float a = acc[mi][g][2][rg];
        const float dr = acc[mi][g][3][rg];
        const float sig = __builtin_amdgcn_rcpf(1.f + __expf(-dr));
        const float z = u * tanh_fast(gt);
        const float am = amax_[idx];
        const float e_neg = __expf(-sig);
        const float a_new = fmaxf(am * e_neg, a);
        const float comm = __expf(am - a_new - sig);  // e_neg * exp(am - a_new)
        const float escal = __expf(a - a_new);
        const float n_new = nt_[idx] * comm + z * escal;
        const float d_new = dt_[idx] * comm + escal;
        const float h_new = tanh_fast(n_new * __builtin_amdgcn_rcpf(d_new));
        out[idx] = n_new;
        out[BC + idx] = d_new;
        out[2 * BC + idx] = h_new;
        out[3 * BC + idx] = a_new;
      }
    }
  }
}

extern "C" void kernel_launch(void* const* d_in, const int* in_sizes, int n_in,
                              void* d_out, int out_size, void* d_ws, size_t ws_size,
                              hipStream_t stream) {
  const float* x_t    = (const float*)d_in[0];
  const float* n_t    = (const float*)d_in[1];
  const float* d_t    = (const float*)d_in[2];
  const float* h_t    = (const float*)d_in[3];
  const float* amax_t = (const float*)d_in[4];
  const float* Wu     = (const float*)d_in[5];
  const float* bu     = (const float*)d_in[6];
  const float* Wg     = (const float*)d_in[7];
  const float* bg     = (const float*)d_in[8];
  const float* Wa     = (const float*)d_in[9];
  const float* Wd     = (const float*)d_in[10];
  float* out = (float*)d_out;

  _Float16* wsB = (_Float16*)d_ws;  // 1 MB packed fragment-major weights

  pack_w<<<256, 256, 0, stream>>>(Wu, Wg, Wa, Wd, wsB);
  rwa_main<<<1024, 256, 0, stream>>>(x_t, n_t, d_t, h_t, amax_t, bu, bg, wsB, out);
}

// Round 5
// 68.249 us; speedup vs baseline: 1.1985x; 1.1985x over previous
//
#include <hip/hip_runtime.h>
#include <stdint.h>

typedef _Float16 f16x8 __attribute__((ext_vector_type(8)));
typedef __fp16 fp16x2 __attribute__((ext_vector_type(2)));
typedef float f32x4 __attribute__((ext_vector_type(4)));

#define BC (16384 * 256)

__device__ __forceinline__ f16x8 cvt8(f32x4 a, f32x4 b) {
  fp16x2 p0 = __builtin_amdgcn_cvt_pkrtz(a[0], a[1]);
  fp16x2 p1 = __builtin_amdgcn_cvt_pkrtz(a[2], a[3]);
  fp16x2 p2 = __builtin_amdgcn_cvt_pkrtz(b[0], b[1]);
  fp16x2 p3 = __builtin_amdgcn_cvt_pkrtz(b[2], b[3]);
  f16x8 o;
  o[0] = (_Float16)p0[0]; o[1] = (_Float16)p0[1];
  o[2] = (_Float16)p1[0]; o[3] = (_Float16)p1[1];
  o[4] = (_Float16)p2[0]; o[5] = (_Float16)p2[1];
  o[6] = (_Float16)p3[0]; o[7] = (_Float16)p3[1];
  return o;
}

__device__ __forceinline__ float tanh_fast(float v) {
  float a = fminf(fabsf(v), 18.f);
  float t = __expf(2.f * a);
  float r = (t - 1.f) * __builtin_amdgcn_rcpf(t + 1.f);
  return copysignf(r, v);
}

// Pack Wu/Wg/Wa/Wd -> wsB f16, PRE-SWIZZLED for the main kernel's LDS scheme.
// Element layout: wsB[cb*65536 + row*512 + kt*64 + slot*8 + b] where
//   row = wn*64 + strip*16 + t16  (packed col index within cb),
//   c   = cb*32 + wn*16 + t16,
//   k   = kt*64 + (slot ^ (row&7))*8 + b   <-- XOR swizzle baked in.
// Main kernel global_load_lds copies this linearly into ldsB[row*128B + slot*16B];
// frag reads use off ^ ((row&7)<<4) -> k-slot = ks*4+lg, matching A's convention.
// strip: 0=Wu (K zero-padded for k>=256), 1=Wg, 2=Wa, 3=Wd.
__global__ __launch_bounds__(256) void pack_w(const float* __restrict__ Wu,
                                              const float* __restrict__ Wg,
                                              const float* __restrict__ Wa,
                                              const float* __restrict__ Wd,
                                              _Float16* __restrict__ wsB) {
  int t = blockIdx.x * 256 + threadIdx.x;  // 65536 total
  int slot = t & 7;
  int kt = (t >> 3) & 7;
  int row = (t >> 6) & 127;
  int cb = t >> 13;
  int strip = (row >> 4) & 3;
  int wn = row >> 6;
  int t16 = row & 15;
  int c = cb * 32 + wn * 16 + t16;
  int k0 = kt * 64 + (slot ^ (row & 7)) * 8;
  float v[8];
  if (strip == 0) {
    if (k0 < 256) {
      const float* p = Wu + (size_t)c * 256 + k0;
#pragma unroll
      for (int i = 0; i < 8; ++i) v[i] = p[i];
    } else {
#pragma unroll
      for (int i = 0; i < 8; ++i) v[i] = 0.f;
    }
  } else {
    const float* p = (strip == 1 ? Wg : (strip == 2 ? Wa : Wd)) + (size_t)c * 512 + k0;
#pragma unroll
    for (int i = 0; i < 8; ++i) v[i] = p[i];
  }
  f32x4 a = {v[0], v[1], v[2], v[3]};
  f32x4 b = {v[4], v[5], v[6], v[7]};
  *reinterpret_cast<f16x8*>(wsB + (size_t)cb * 65536 + row * 512 + kt * 64 + slot * 8) =
      cvt8(a, b);
}

// m97-structure fused GEMM [16384,512]x[512,1024] f16 + epilogue.
// Block: 128 rows x 128 packed cols (32 c x 4 strips), 4 waves (2M x 2N),
// BK=64, single-buffered 32 KB LDS, 2 barriers per K-step.
// B: global_load_lds dwordx4 (pre-swizzled source). A: reg-staged f32->f16.
__global__ __launch_bounds__(256, 4) void rwa_main(
    const float* __restrict__ x, const float* __restrict__ nt_,
    const float* __restrict__ dt_, const float* __restrict__ h,
    const float* __restrict__ amax_, const float* __restrict__ bu,
    const float* __restrict__ bg, const _Float16* __restrict__ wsB,
    float* __restrict__ out) {
  __shared__ __align__(16) _Float16 ldsA[128 * 64];  // 16 KB
  __shared__ __align__(16) _Float16 ldsB[128 * 64];  // 16 KB

  const int tid = threadIdx.x;
  const int lane = tid & 63;
  const int l15 = lane & 15;
  const int lg = lane >> 4;
  const int wv = tid >> 6;
  const int wm = wv & 1;   // wave row-half
  const int wn = wv >> 1;  // wave col-half (packed)

  // XCD swizzle: per XCD, cb fastest -> A row-panel (256 KB) and B (1 MB) L2-hot.
  const int bid = blockIdx.x;
  const int xcd = bid & 7;
  const int q = bid >> 3;          // 0..127
  const int cb = q & 7;            // B col-block
  const int rowblk = xcd * 16 + (q >> 3);
  const int row0 = rowblk * 128;

  // A staging: thread t stages row ar = t>>1, k-half ah = t&1 (32 floats).
  const int ar = tid >> 1;
  const int ah = tid & 1;

  // B staging source base (element offset); per i: +16384, per kt: +64.
  const _Float16* bsrc0 = wsB + (size_t)cb * 65536 + (tid >> 3) * 512 + (tid & 7) * 8;

  f32x4 acc[4][4] = {};  // [mi][strip]

  for (int kt = 0; kt < 8; ++kt) {
    // --- stage B: 4x global_load_lds dwordx4 (linear LDS dest) ---
#pragma unroll
    for (int i = 0; i < 4; ++i) {
      __builtin_amdgcn_global_load_lds(
          (const __attribute__((address_space(1))) uint32_t*)(bsrc0 + i * 16384 + kt * 64),
          (__attribute__((address_space(3))) uint32_t*)(ldsB + wv * 512 + i * 2048),
          16, 0, 0);
    }
    // --- stage A: coalesced f32 loads, cvt to f16, swizzled ds_write ---
    {
      const float* asrc =
          (kt < 4 ? x : h) + (size_t)(row0 + ar) * 256 + (kt & 3) * 64 + ah * 32;
      f32x4 av[8];
#pragma unroll
      for (int i = 0; i < 8; ++i) av[i] = *reinterpret_cast<const f32x4*>(asrc + i * 4);
#pragma unroll
      for (int j = 0; j < 4; ++j) {
        f16x8 o = cvt8(av[2 * j], av[2 * j + 1]);
        const int slot = (ah * 4 + j) ^ (ar & 7);
        *reinterpret_cast<f16x8*>(reinterpret_cast<char*>(ldsA) + ar * 128 + slot * 16) = o;
      }
    }
    __syncthreads();

    // --- compute ---
    const bool doU = (kt < 4);  // Wu strip zero-padded beyond k=256
    const int rswz = (l15 & 7) << 4;
#pragma unroll
    for (int ks = 0; ks < 2; ++ks) {
      f16x8 af[4], bf[4];
#pragma unroll
      for (int mi = 0; mi < 4; ++mi) {
        const int row = wm * 64 + mi * 16 + l15;
        af[mi] = *reinterpret_cast<const f16x8*>(
            reinterpret_cast<const char*>(ldsA) + row * 128 + ((ks * 64 + lg * 16) ^ rswz));
      }
#pragma unroll
      for (int s = 0; s < 4; ++s) {
        if (s == 0 && !doU) continue;
        const int row = wn * 64 + s * 16 + l15;
        bf[s] = *reinterpret_cast<const f16x8*>(
            reinterpret_cast<const char*>(ldsB) + row * 128 + ((ks * 64 + lg * 16) ^ rswz));
      }
#pragma unroll
      for (int s = 0; s < 4; ++s) {
        if (s == 0 && !doU) continue;
#pragma unroll
        for (int mi = 0; mi < 4; ++mi)
          acc[mi][s] = __builtin_amdgcn_mfma_f32_16x16x32_f16(af[mi], bf[s], acc[mi][s], 0, 0, 0);
      }
    }
    __syncthreads();
  }

  // --- epilogue: lane owns (r,c) with u,g,a,dec local ---
  const int c = cb * 32 + wn * 16 + l15;
  const float buv = bu[c];
  const float bgv = bg[c];
#pragma unroll
  for (int mi = 0; mi < 4; ++mi) {
#pragma unroll
    for (int rg = 0; rg < 4; ++rg) {
      const int r = row0 + wm * 64 + mi * 16 + lg * 4 + rg;
      const int idx = r * 256 + c;
      const float u = acc[mi][0][rg] + buv;
      const float gt = acc[mi][1][rg] + bgv;
      const float a = acc[mi][2][rg];
      const float dr = acc[mi][3][rg];
      const float sig = __builtin_amdgcn_rcpf(1.f + __expf(-dr));
      const float z = u * tanh_fast(gt);
      const float am = amax_[idx];
      const float e_neg = __expf(-sig);
      const float a_new = fmaxf(am * e_neg, a);
      const float comm = __expf(am - a_new - sig);  // e_neg * exp(am - a_new)
      const float escal = __expf(a - a_new);
      const float n_new = nt_[idx] * comm + z * escal;
      const float d_new = dt_[idx] * comm + escal;
      const float h_new = tanh_fast(n_new * __builtin_amdgcn_rcpf(d_new));
      out[idx] = n_new;
      out[BC + idx] = d_new;
      out[2 * BC + idx] = h_new;
      out[3 * BC + idx] = a_new;
    }
  }
}

extern "C" void kernel_launch(void* const* d_in, const int* in_sizes, int n_in,
                              void* d_out, int out_size, void* d_ws, size_t ws_size,
                              hipStream_t stream) {
  const float* x_t    = (const float*)d_in[0];
  const float* n_t    = (const float*)d_in[1];
  const float* d_t    = (const float*)d_in[2];
  const float* h_t    = (const float*)d_in[3];
  const float* amax_t = (const float*)d_in[4];
  const float* Wu     = (const float*)d_in[5];
  const float* bu     = (const float*)d_in[6];
  const float* Wg     = (const float*)d_in[7];
  const float* bg     = (const float*)d_in[8];
  const float* Wa     = (const float*)d_in[9];
  const float* Wd     = (const float*)d_in[10];
  float* out = (float*)d_out;

  _Float16* wsB = (_Float16*)d_ws;  // 1 MB pre-swizzled packed weights

  pack_w<<<256, 256, 0, stream>>>(Wu, Wg, Wa, Wd, wsB);
  rwa_main<<<1024, 256, 0, stream>>>(x_t, n_t, d_t, h_t, amax_t, bu, bg, wsB, out);
}

// Round 6
// 52.647 us; speedup vs baseline: 1.5537x; 1.2964x over previous
//
#include <hip/hip_runtime.h>
#include <stdint.h>

typedef _Float16 f16x8 __attribute__((ext_vector_type(8)));
typedef __fp16 fp16x2 __attribute__((ext_vector_type(2)));
typedef float f32x4 __attribute__((ext_vector_type(4)));

#define BC (16384 * 256)

__device__ __forceinline__ f16x8 cvt8(f32x4 a, f32x4 b) {
  fp16x2 p0 = __builtin_amdgcn_cvt_pkrtz(a[0], a[1]);
  fp16x2 p1 = __builtin_amdgcn_cvt_pkrtz(a[2], a[3]);
  fp16x2 p2 = __builtin_amdgcn_cvt_pkrtz(b[0], b[1]);
  fp16x2 p3 = __builtin_amdgcn_cvt_pkrtz(b[2], b[3]);
  f16x8 o;
  o[0] = (_Float16)p0[0]; o[1] = (_Float16)p0[1];
  o[2] = (_Float16)p1[0]; o[3] = (_Float16)p1[1];
  o[4] = (_Float16)p2[0]; o[5] = (_Float16)p2[1];
  o[6] = (_Float16)p3[0]; o[7] = (_Float16)p3[1];
  return o;
}

__device__ __forceinline__ float tanh_fast(float v) {
  float a = fminf(fabsf(v), 18.f);
  float t = __expf(2.f * a);
  float r = (t - 1.f) * __builtin_amdgcn_rcpf(t + 1.f);
  return copysignf(r, v);
}

// Pack Wu/Wg/Wa/Wd -> wsB f16, PRE-SWIZZLED (unchanged from R5, verified).
// wsB[cb*65536 + row*512 + kt*64 + slot*8 + b] where
//   row = wn*64 + strip*16 + t16, c = cb*32 + wn*16 + t16,
//   k = kt*64 + (slot ^ (row&7))*8 + b  (XOR swizzle baked in).
// strip: 0=Wu (K zero-padded for k>=256), 1=Wg, 2=Wa, 3=Wd.
__global__ __launch_bounds__(256) void pack_w(const float* __restrict__ Wu,
                                              const float* __restrict__ Wg,
                                              const float* __restrict__ Wa,
                                              const float* __restrict__ Wd,
                                              _Float16* __restrict__ wsB) {
  int t = blockIdx.x * 256 + threadIdx.x;  // 65536 total
  int slot = t & 7;
  int kt = (t >> 3) & 7;
  int row = (t >> 6) & 127;
  int cb = t >> 13;
  int strip = (row >> 4) & 3;
  int wn = row >> 6;
  int t16 = row & 15;
  int c = cb * 32 + wn * 16 + t16;
  int k0 = kt * 64 + (slot ^ (row & 7)) * 8;
  float v[8];
  if (strip == 0) {
    if (k0 < 256) {
      const float* p = Wu + (size_t)c * 256 + k0;
#pragma unroll
      for (int i = 0; i < 8; ++i) v[i] = p[i];
    } else {
#pragma unroll
      for (int i = 0; i < 8; ++i) v[i] = 0.f;
    }
  } else {
    const float* p = (strip == 1 ? Wg : (strip == 2 ? Wa : Wd)) + (size_t)c * 512 + k0;
#pragma unroll
    for (int i = 0; i < 8; ++i) v[i] = p[i];
  }
  f32x4 a = {v[0], v[1], v[2], v[3]};
  f32x4 b = {v[4], v[5], v[6], v[7]};
  *reinterpret_cast<f16x8*>(wsB + (size_t)cb * 65536 + row * 512 + kt * 64 + slot * 8) =
      cvt8(a, b);
}

// Occupancy-first fused GEMM + epilogue.
// Block: 64 rows x 128 packed cols, 4 waves (2M x 2N), BK=64, 24 KB LDS
// -> 6 blocks/CU co-resident; block-level TLP is the pipeline.
__global__ __launch_bounds__(256, 6) void rwa_main(
    const float* __restrict__ x, const float* __restrict__ nt_,
    const float* __restrict__ dt_, const float* __restrict__ h,
    const float* __restrict__ amax_, const float* __restrict__ bu,
    const float* __restrict__ bg, const _Float16* __restrict__ wsB,
    float* __restrict__ out) {
  __shared__ __align__(16) _Float16 ldsA[64 * 64];   // 8 KB
  __shared__ __align__(16) _Float16 ldsB[128 * 64];  // 16 KB

  const int tid = threadIdx.x;
  const int lane = tid & 63;
  const int l15 = lane & 15;
  const int lg = lane >> 4;
  const int wv = tid >> 6;
  const int wm = wv & 1;   // wave row-half (32 rows)
  const int wn = wv >> 1;  // wave packed-col half (64)

  // XCD swizzle: per XCD, cb fastest -> row panels + 1 MB weights L2-hot.
  const int bid = blockIdx.x;
  const int xcd = bid & 7;
  const int q = bid >> 3;  // 0..255
  const int cb = q & 7;
  const int rowblk = xcd * 32 + (q >> 3);
  const int row0 = rowblk * 64;

  // A staging: thread stages row ar (0..63), quarter aq (16 floats).
  const int ar = tid >> 2;
  const int aq = tid & 3;

  // B staging source base (element offset); per i: +16384 (32 rows), per kt: +64.
  const _Float16* bsrc0 = wsB + (size_t)cb * 65536 + (tid >> 3) * 512 + (tid & 7) * 8;

  f32x4 acc[2][4] = {};  // [mi][strip]

  for (int kt = 0; kt < 8; ++kt) {
    // --- stage B: 4x global_load_lds dwordx4 (linear dest, pre-swizzled src) ---
#pragma unroll
    for (int i = 0; i < 4; ++i) {
      __builtin_amdgcn_global_load_lds(
          (const __attribute__((address_space(1))) uint32_t*)(bsrc0 + i * 16384 + kt * 64),
          (__attribute__((address_space(3))) uint32_t*)(ldsB + wv * 512 + i * 2048),
          16, 0, 0);
    }
    // --- stage A: coalesced f32 loads, cvt f16, swizzled ds_write ---
    {
      const float* asrc =
          (kt < 4 ? x : h) + (size_t)(row0 + ar) * 256 + (kt & 3) * 64 + aq * 16;
      f32x4 av[4];
#pragma unroll
      for (int i = 0; i < 4; ++i) av[i] = *reinterpret_cast<const f32x4*>(asrc + i * 4);
#pragma unroll
      for (int j = 0; j < 2; ++j) {
        f16x8 o = cvt8(av[2 * j], av[2 * j + 1]);
        const int slot = (aq * 2 + j) ^ (ar & 7);
        *reinterpret_cast<f16x8*>(reinterpret_cast<char*>(ldsA) + ar * 128 + slot * 16) = o;
      }
    }
    __syncthreads();

    // --- compute ---
    const bool doU = (kt < 4);  // Wu strip zero-padded beyond k=256
    const int rswz = (l15 & 7) << 4;
#pragma unroll
    for (int ks = 0; ks < 2; ++ks) {
      f16x8 af[2], bf[4];
#pragma unroll
      for (int mi = 0; mi < 2; ++mi) {
        const int row = wm * 32 + mi * 16 + l15;
        af[mi] = *reinterpret_cast<const f16x8*>(
            reinterpret_cast<const char*>(ldsA) + row * 128 + ((ks * 64 + lg * 16) ^ rswz));
      }
#pragma unroll
      for (int s = 0; s < 4; ++s) {
        if (s == 0 && !doU) continue;
        const int row = wn * 64 + s * 16 + l15;
        bf[s] = *reinterpret_cast<const f16x8*>(
            reinterpret_cast<const char*>(ldsB) + row * 128 + ((ks * 64 + lg * 16) ^ rswz));
      }
#pragma unroll
      for (int s = 0; s < 4; ++s) {
        if (s == 0 && !doU) continue;
#pragma unroll
        for (int mi = 0; mi < 2; ++mi)
          acc[mi][s] = __builtin_amdgcn_mfma_f32_16x16x32_f16(af[mi], bf[s], acc[mi][s], 0, 0, 0);
      }
    }
    __syncthreads();
  }

  // --- epilogue: lane owns (r,c) with u,g,a,dec local ---
  const int c = cb * 32 + wn * 16 + l15;
  const float buv = bu[c];
  const float bgv = bg[c];
#pragma unroll
  for (int mi = 0; mi < 2; ++mi) {
#pragma unroll
    for (int rg = 0; rg < 4; ++rg) {
      const int r = row0 + wm * 32 + mi * 16 + lg * 4 + rg;
      const int idx = r * 256 + c;
      const float u = acc[mi][0][rg] + buv;
      const float gt = acc[mi][1][rg] + bgv;
      const float a = acc[mi][2][rg];
      const float dr = acc[mi][3][rg];
      const float sig = __builtin_amdgcn_rcpf(1.f + __expf(-dr));
      const float z = u * tanh_fast(gt);
      const float am = amax_[idx];
      const float e_neg = __expf(-sig);
      const float a_new = fmaxf(am * e_neg, a);
      const float comm = __expf(am - a_new - sig);  // e_neg * exp(am - a_new)
      const float escal = __expf(a - a_new);
      const float n_new = nt_[idx] * comm + z * escal;
      const float d_new = dt_[idx] * comm + escal;
      const float h_new = tanh_fast(n_new * __builtin_amdgcn_rcpf(d_new));
      out[idx] = n_new;
      out[BC + idx] = d_new;
      out[2 * BC + idx] = h_new;
      out[3 * BC + idx] = a_new;
    }
  }
}

extern "C" void kernel_launch(void* const* d_in, const int* in_sizes, int n_in,
                              void* d_out, int out_size, void* d_ws, size_t ws_size,
                              hipStream_t stream) {
  const float* x_t    = (const float*)d_in[0];
  const float* n_t    = (const float*)d_in[1];
  const float* d_t    = (const float*)d_in[2];
  const float* h_t    = (const float*)d_in[3];
  const float* amax_t = (const float*)d_in[4];
  const float* Wu     = (const float*)d_in[5];
  const float* bu     = (const float*)d_in[6];
  const float* Wg     = (const float*)d_in[7];
  const float* bg     = (const float*)d_in[8];
  const float* Wa     = (const float*)d_in[9];
  const float* Wd     = (const float*)d_in[10];
  float* out = (float*)d_out;

  _Float16* wsB = (_Float16*)d_ws;  // 1 MB pre-swizzled packed weights

  pack_w<<<256, 256, 0, stream>>>(Wu, Wg, Wa, Wd, wsB);
  rwa_main<<<2048, 256, 0, stream>>>(x_t, n_t, d_t, h_t, amax_t, bu, bg, wsB, out);
}